// Round 6
// baseline (4706.998 us; speedup 1.0000x reference)
//
#include <hip/hip_runtime.h>

#define Bsz 128
#define Tlen 1024
#define Din 256
#define Hdim 512

#define NBG 8    // batch groups (16 rows each)
#define NCG 32   // col groups (16 h-cols each)

typedef __attribute__((ext_vector_type(8))) short short8;
typedef __attribute__((ext_vector_type(4))) float f32x4;
typedef __attribute__((ext_vector_type(4))) unsigned short ushort4_;
typedef __attribute__((ext_vector_type(4))) unsigned int uint4v;

// tagged h exchange: u32 = (bf16<<16) | tag ; layout [2 parity][NBG][16 rows][512 cols]
#define HBT_BYTES ((size_t)2 * NBG * 16 * Hdim * 4)  // 524,288
#define HT_OFF ((size_t)524288)

__device__ inline unsigned short f2bf(float f) {
    unsigned int u = __builtin_bit_cast(unsigned int, f);
    unsigned int lsb = (u >> 16) & 1u;
    u += 0x7fffu + lsb;  // RNE
    return (unsigned short)(u >> 16);
}
__device__ inline float bf2f(unsigned short u) {
    unsigned int v = ((unsigned int)u) << 16;
    return __builtin_bit_cast(float, v);
}
__device__ inline float sigm_f(float x) { return 1.f / (1.f + __expf(-x)); }
__device__ inline float tanh_f(float x) { return 1.f - 2.f / (__expf(2.f * x) + 1.f); }

__device__ __forceinline__ void conv_x_to_lds(const float4* xv, int tid,
                                              unsigned char* xh, unsigned char* xl) {
#pragma unroll
    for (int i = 0; i < 4; i++) {
        int cidx = tid + i * 256;
        int row = cidx >> 6;
        int c4 = cidx & 63;
        float vv[4] = {xv[i].x, xv[i].y, xv[i].z, xv[i].w};
        ushort4_ vh, vl;
#pragma unroll
        for (int e = 0; e < 4; e++) {
            unsigned short hi = f2bf(vv[e]);
            vh[e] = hi;
            vl[e] = f2bf(vv[e] - bf2f(hi));
        }
        int a = ((row << 9) + (c4 << 3)) ^ ((row & 7) << 4);
        *(ushort4_*)(xh + a) = vh;
        *(ushort4_*)(xl + a) = vl;
    }
}

// chunk valid iff all 4 words carry tag == want (per-4B-word atomicity)
__device__ __forceinline__ bool chunk_ok(uint4v v, unsigned want) {
    unsigned m =
        ((v[0] ^ want) | (v[1] ^ want) | (v[2] ^ want) | (v[3] ^ want)) & 0xFFFFu;
    return m == 0;
}
// extract 4 bf16 (high halves) -> 8B into swizzled h_lds
__device__ __forceinline__ void chunk_to_lds(uint4v v, int c, unsigned char* h_lds) {
    int row = c >> 7;
    unsigned lo = (v[0] >> 16) | (v[1] & 0xFFFF0000u);
    unsigned hi = (v[2] >> 16) | (v[3] & 0xFFFF0000u);
    int a = ((row << 10) + ((c & 127) << 3)) ^ ((row & 7) << 4);
    *(unsigned long long*)(h_lds + a) =
        (unsigned long long)lo | ((unsigned long long)hi << 32);
}

__global__ __launch_bounds__(256, 1) void lstm_persist(
    const float* __restrict__ x, const float* __restrict__ Wih,
    const float* __restrict__ Whh, const float* __restrict__ bih,
    const float* __restrict__ bhh, unsigned int* __restrict__ hbt,
    float* __restrict__ hT) {
    __shared__ unsigned char h_lds[16 * 1024];   // [16][512] bf16, swizzled
    __shared__ unsigned char xh_lds[2 * 8192];   // dbuf [16][256] bf16 hi, swizzled
    __shared__ unsigned char xl_lds[2 * 8192];   // dbuf lo
    __shared__ float gates_w[4][16 * 17];        // per-wave [16 batch][16 gcol]

    const int tid = threadIdx.x;
    const int bid = blockIdx.x;
    const int bg = bid & 7;
    const int cg = bid >> 3;
    const int lane = tid & 63;
    const int w = tid >> 6;
    const int n15 = lane & 15;
    const int k8 = lane >> 4;
    const int grow = bg * 16;
    // wave owns all 4 gates for 4 h-cols: lane -> (batch myb, col mycol)
    const int gc = n15 & 3;
    const int gsel = n15 >> 2;
    const int myb = k8 * 4 + gsel;
    const int mycol = cg * 16 + w * 4 + gc;

    // ---- one-time: weight fragments. B-frag col n15 -> gate-row R ----
    const int R = (n15 >> 2) * Hdim + mycol;
    short8 whh[16], wihh[8], wihl[8];
    {
        const float* wr = Whh + (size_t)R * Hdim;
#pragma unroll
        for (int kc = 0; kc < 16; kc++) {
            const float* p = wr + kc * 32 + k8 * 8;
            short8 f;
#pragma unroll
            for (int e = 0; e < 8; e++) f[e] = (short)f2bf(p[e]);
            whh[kc] = f;
        }
        const float* wr2 = Wih + (size_t)R * Din;
#pragma unroll
        for (int kc = 0; kc < 8; kc++) {
            const float* p = wr2 + kc * 32 + k8 * 8;
            short8 fh, fl;
#pragma unroll
            for (int e = 0; e < 8; e++) {
                float v = p[e];
                unsigned short hi = f2bf(v);
                fh[e] = (short)hi;
                fl[e] = (short)f2bf(v - bf2f(hi));
            }
            wihh[kc] = fh;
            wihl[kc] = fl;
        }
    }
    float bias4[4];
#pragma unroll
    for (int g = 0; g < 4; g++) bias4[g] = bih[g * Hdim + mycol] + bhh[g * Hdim + mycol];

    // ---- prologue: stage x[0] -> buf0; prefetch x[1] -> regs ----
    float4 xr[4];
    {
        const float* xb = x + (size_t)grow * (Tlen * Din);
#pragma unroll
        for (int i = 0; i < 4; i++) {
            int cidx = tid + i * 256;
            int row = cidx >> 6;
            int c4 = cidx & 63;
            xr[i] = *(const float4*)(xb + (size_t)row * (Tlen * Din) + c4 * 4);
        }
        conv_x_to_lds(xr, tid, xh_lds, xl_lds);
#pragma unroll
        for (int i = 0; i < 4; i++) {
            int cidx = tid + i * 256;
            int row = cidx >> 6;
            int c4 = cidx & 63;
            xr[i] = *(const float4*)(xb + (size_t)row * (Tlen * Din) + Din + c4 * 4);
        }
    }
    __syncthreads();

    float c_reg = 0.f, h_last = 0.f;

    for (int t = 0; t < Tlen; ++t) {
        // (1) convert xr (= x[t+1]) into buf[(t+1)&1]
        if (t + 1 < Tlen)
            conv_x_to_lds(xr, tid, xh_lds + ((t + 1) & 1) * 8192,
                          xl_lds + ((t + 1) & 1) * 8192);

        // (2) issue first tagged-data sweep (no wait; flight covered by x-MFMAs)
        const unsigned int* hb = hbt + ((size_t)(t & 1) * NBG + bg) * 8192;
        const unsigned int* p[8];
#pragma unroll
        for (int i = 0; i < 8; i++) p[i] = hb + (size_t)(tid + i * 256) * 4;
        uint4v r0, r1, r2, r3, r4, r5, r6, r7;
        if (t > 0) {
            asm volatile(
                "global_load_dwordx4 %0, %8, off sc0 sc1\n\t"
                "global_load_dwordx4 %1, %9, off sc0 sc1\n\t"
                "global_load_dwordx4 %2, %10, off sc0 sc1\n\t"
                "global_load_dwordx4 %3, %11, off sc0 sc1\n\t"
                "global_load_dwordx4 %4, %12, off sc0 sc1\n\t"
                "global_load_dwordx4 %5, %13, off sc0 sc1\n\t"
                "global_load_dwordx4 %6, %14, off sc0 sc1\n\t"
                "global_load_dwordx4 %7, %15, off sc0 sc1"
                : "=&v"(r0), "=&v"(r1), "=&v"(r2), "=&v"(r3), "=&v"(r4), "=&v"(r5),
                  "=&v"(r6), "=&v"(r7)
                : "v"(p[0]), "v"(p[1]), "v"(p[2]), "v"(p[3]), "v"(p[4]), "v"(p[5]),
                  "v"(p[6]), "v"(p[7])
                : "memory");
        }

        // (3) x-side MFMAs on buf[t&1] (cover the sweep flight)
        unsigned char* xh = xh_lds + (t & 1) * 8192;
        unsigned char* xl = xl_lds + (t & 1) * 8192;
        f32x4 acc0 = {0.f, 0.f, 0.f, 0.f}, acc1 = {0.f, 0.f, 0.f, 0.f};
#pragma unroll
        for (int kc = 0; kc < 8; kc++) {
            int a = ((n15 << 9) + (kc << 6) + (k8 << 4)) ^ ((n15 & 7) << 4);
            short8 xhv = *(const short8*)(xh + a);
            short8 xlv = *(const short8*)(xl + a);
            acc0 = __builtin_amdgcn_mfma_f32_16x16x32_bf16(xhv, wihh[kc], acc0, 0, 0, 0);
            acc1 = __builtin_amdgcn_mfma_f32_16x16x32_bf16(xlv, wihh[kc], acc1, 0, 0, 0);
            if (kc & 1)
                acc1 = __builtin_amdgcn_mfma_f32_16x16x32_bf16(xhv, wihl[kc], acc1, 0, 0, 0);
            else
                acc0 = __builtin_amdgcn_mfma_f32_16x16x32_bf16(xhv, wihl[kc], acc0, 0, 0, 0);
        }

        // (4) validate tags; extract into h_lds; retry failed chunks
        if (t > 0) {
            const unsigned want = (unsigned)t;
            asm volatile("s_waitcnt vmcnt(0)" ::: "memory");
            __builtin_amdgcn_sched_barrier(0);
            unsigned need = 0;
#pragma unroll
            for (int i = 0; i < 8; i++) {
                uint4v v = (i == 0) ? r0 : (i == 1) ? r1 : (i == 2) ? r2 : (i == 3) ? r3
                           : (i == 4) ? r4 : (i == 5) ? r5 : (i == 6) ? r6 : r7;
                if (__all(chunk_ok(v, want)))
                    chunk_to_lds(v, tid + i * 256, h_lds);
                else
                    need |= (1u << i);
            }
            int rounds = 0;
            while (need && ++rounds < 20000) {
                if (rounds > 2) __builtin_amdgcn_s_sleep(4);
#pragma unroll
                for (int i = 0; i < 8; i++) {
                    if (need & (1u << i)) {
                        uint4v v;
                        asm volatile(
                            "global_load_dwordx4 %0, %1, off sc0 sc1\n\t"
                            "s_waitcnt vmcnt(0)"
                            : "=&v"(v)
                            : "v"(p[i])
                            : "memory");
                        __builtin_amdgcn_sched_barrier(0);
                        if (__all(chunk_ok(v, want))) {
                            chunk_to_lds(v, tid + i * 256, h_lds);
                            need &= ~(1u << i);
                        }
                    }
                }
            }
        } else {
#pragma unroll
            for (int i = 0; i < 8; i++) {
                int c = tid + i * 256;
                int row = c >> 7;
                int a = ((row << 10) + ((c & 127) << 3)) ^ ((row & 7) << 4);
                *(unsigned long long*)(h_lds + a) = 0ULL;
            }
        }
        __syncthreads();  // A: h_lds ready

        // (5) h-side MFMAs
#pragma unroll
        for (int kc = 0; kc < 16; kc++) {
            short8 a = *(const short8*)(h_lds + (((n15 << 10) + (kc << 6) + (k8 << 4)) ^
                                                ((n15 & 7) << 4)));
            if (kc & 1)
                acc1 = __builtin_amdgcn_mfma_f32_16x16x32_bf16(a, whh[kc], acc1, 0, 0, 0);
            else
                acc0 = __builtin_amdgcn_mfma_f32_16x16x32_bf16(a, whh[kc], acc0, 0, 0, 0);
        }

        // (6) prefetch x[t+2] (covered by cell phase; consumed at (1) next step)
        if (t + 2 < Tlen) {
            const float* xb = x + (size_t)grow * (Tlen * Din) + (size_t)(t + 2) * Din;
#pragma unroll
            for (int i = 0; i < 4; i++) {
                int cidx = tid + i * 256;
                int row = cidx >> 6;
                int c4 = cidx & 63;
                xr[i] = *(const float4*)(xb + (size_t)row * (Tlen * Din) + c4 * 4);
            }
        }

        // (7) gates to wave-PRIVATE LDS tile; cell update; tagged publish
        float* gt = gates_w[w];
#pragma unroll
        for (int j2 = 0; j2 < 4; j2++) gt[(k8 * 4 + j2) * 17 + n15] = acc0[j2] + acc1[j2];
        {
            float pre[4];
#pragma unroll
            for (int g = 0; g < 4; g++) pre[g] = gt[myb * 17 + g * 4 + gc] + bias4[g];
            float ig = sigm_f(pre[0]);
            float fg = sigm_f(pre[1]);
            float gg = tanh_f(pre[2]);
            float og = sigm_f(pre[3]);
            c_reg = fg * c_reg + ig * gg;
            h_last = og * tanh_f(c_reg);
            // fire-and-forget tagged store: (bf16<<16) | (t+1)
            unsigned int word = ((unsigned int)f2bf(h_last) << 16) | (unsigned)(t + 1);
            unsigned int* dst = hbt + ((size_t)((t + 1) & 1) * NBG + bg) * 8192 +
                                (size_t)myb * Hdim + mycol;
            __hip_atomic_store(dst, word, __ATOMIC_RELAXED, __HIP_MEMORY_SCOPE_AGENT);
        }
        __syncthreads();  // C: clears LDS WAR hazards for next step
    }

    hT[(size_t)(grow + myb) * Hdim + mycol] = h_last;
}

__global__ __launch_bounds__(256) void out_proj(const float* __restrict__ hT,
                                                const float* __restrict__ Wout,
                                                const float* __restrict__ bout,
                                                float* __restrict__ out) {
    __shared__ float h_s[16 * 512];
    __shared__ float w_s[64 * 69];
    const int tid = threadIdx.x;
    const int bt = blockIdx.x >> 2;
    const int ot = blockIdx.x & 3;
#pragma unroll
    for (int i = 0; i < 8; i++) {
        int cidx = tid + i * 256;
        int row = cidx >> 7;
        int c4 = cidx & 127;
        *(float4*)(&h_s[row * 512 + c4 * 4]) =
            *(const float4*)(hT + (size_t)(bt * 16 + row) * 512 + c4 * 4);
    }
    const int o = tid & 63;
    const int bq = tid >> 6;
    float acc[4] = {0.f, 0.f, 0.f, 0.f};
    for (int kc = 0; kc < 8; kc++) {
        __syncthreads();
#pragma unroll
        for (int i = 0; i < 4; i++) {
            int cidx = tid + i * 256;
            int row = cidx >> 4;
            int c4 = cidx & 15;
            float4 v = *(const float4*)(Wout + (size_t)(ot * 64 + row) * 512 + kc * 64 +
                                        c4 * 4);
            float* dst = &w_s[row * 69 + c4 * 4];
            dst[0] = v.x;
            dst[1] = v.y;
            dst[2] = v.z;
            dst[3] = v.w;
        }
        __syncthreads();
#pragma unroll 16
        for (int k = 0; k < 64; k++) {
            float wv = w_s[o * 69 + k];
#pragma unroll
            for (int bi = 0; bi < 4; bi++)
                acc[bi] += h_s[(bq * 4 + bi) * 512 + kc * 64 + k] * wv;
        }
    }
    float bo = bout[ot * 64 + o];
#pragma unroll
    for (int bi = 0; bi < 4; bi++)
        out[(size_t)(bt * 16 + bq * 4 + bi) * 256 + ot * 64 + o] = acc[bi] + bo;
}

extern "C" void kernel_launch(void* const* d_in, const int* in_sizes, int n_in,
                              void* d_out, int out_size, void* d_ws, size_t ws_size,
                              hipStream_t stream) {
    const float* x = (const float*)d_in[0];
    const float* Wih = (const float*)d_in[1];
    const float* Whh = (const float*)d_in[2];
    const float* bih = (const float*)d_in[3];
    const float* bhh = (const float*)d_in[4];
    const float* Wout = (const float*)d_in[5];
    const float* bout = (const float*)d_in[6];
    float* out = (float*)d_out;

    char* ws = (char*)d_ws;
    unsigned int* hbt = (unsigned int*)ws;
    float* hT = (float*)(ws + HT_OFF);

    hipMemsetAsync(hbt, 0, HBT_BYTES, stream);  // clear tags: replay determinism
    lstm_persist<<<dim3(256), dim3(256), 0, stream>>>(x, Wih, Whh, bih, bhh, hbt, hT);
    out_proj<<<dim3(32), dim3(256), 0, stream>>>(hT, Wout, bout, out);
}

// Round 7
// 2175.615 us; speedup vs baseline: 2.1635x; 2.1635x over previous
//
#include <hip/hip_runtime.h>

#define Bsz 128
#define Tlen 1024
#define Din 256
#define Hdim 512

#define NBG 8    // batch groups (16 rows each)
#define NCG 16   // col groups per bg (32 h-cols each, 512-thread WGs)

typedef __attribute__((ext_vector_type(8))) short short8;
typedef __attribute__((ext_vector_type(4))) float f32x4;
typedef __attribute__((ext_vector_type(4))) unsigned short ushort4_;
typedef __attribute__((ext_vector_type(4))) unsigned int uint4v;

// tagged h exchange: u32 = (bf16<<16) | tag ; layout [2 parity][NBG][16 rows][512 cols]
#define HBT_BYTES ((size_t)2 * NBG * 16 * Hdim * 4)  // 524,288
#define HT_OFF ((size_t)524288)

__device__ inline unsigned short f2bf(float f) {
    unsigned int u = __builtin_bit_cast(unsigned int, f);
    unsigned int lsb = (u >> 16) & 1u;
    u += 0x7fffu + lsb;  // RNE
    return (unsigned short)(u >> 16);
}
__device__ inline float bf2f(unsigned short u) {
    unsigned int v = ((unsigned int)u) << 16;
    return __builtin_bit_cast(float, v);
}
__device__ inline float sigm_f(float x) { return 1.f / (1.f + __expf(-x)); }
__device__ inline float tanh_f(float x) { return 1.f - 2.f / (__expf(2.f * x) + 1.f); }

// 512-thread version: 2 chunks per thread
__device__ __forceinline__ void conv_x_to_lds(const float4* xv, int tid,
                                              unsigned char* xh, unsigned char* xl) {
#pragma unroll
    for (int i = 0; i < 2; i++) {
        int cidx = tid + i * 512;
        int row = cidx >> 6;
        int c4 = cidx & 63;
        float vv[4] = {xv[i].x, xv[i].y, xv[i].z, xv[i].w};
        ushort4_ vh, vl;
#pragma unroll
        for (int e = 0; e < 4; e++) {
            unsigned short hi = f2bf(vv[e]);
            vh[e] = hi;
            vl[e] = f2bf(vv[e] - bf2f(hi));
        }
        int a = ((row << 9) + (c4 << 3)) ^ ((row & 7) << 4);
        *(ushort4_*)(xh + a) = vh;
        *(ushort4_*)(xl + a) = vl;
    }
}

// chunk valid iff all 4 words carry tag == want (per-4B-word atomicity)
__device__ __forceinline__ bool chunk_ok(uint4v v, unsigned want) {
    unsigned m =
        ((v[0] ^ want) | (v[1] ^ want) | (v[2] ^ want) | (v[3] ^ want)) & 0xFFFFu;
    return m == 0;
}
// extract 4 bf16 (high halves) -> 8B into swizzled h_lds ; c in [0,2048)
__device__ __forceinline__ void chunk_to_lds(uint4v v, int c, unsigned char* h_lds) {
    int row = c >> 7;
    unsigned lo = (v[0] >> 16) | (v[1] & 0xFFFF0000u);
    unsigned hi = (v[2] >> 16) | (v[3] & 0xFFFF0000u);
    int a = ((row << 10) + ((c & 127) << 3)) ^ ((row & 7) << 4);
    *(unsigned long long*)(h_lds + a) =
        (unsigned long long)lo | ((unsigned long long)hi << 32);
}

__global__ __launch_bounds__(512, 1) void lstm_persist(
    const float* __restrict__ x, const float* __restrict__ Wih,
    const float* __restrict__ Whh, const float* __restrict__ bih,
    const float* __restrict__ bhh, unsigned int* __restrict__ hbt,
    float* __restrict__ hT) {
    __shared__ unsigned char h_lds[16 * 1024];   // [16][512] bf16, swizzled
    __shared__ unsigned char xh_lds[2 * 8192];   // dbuf [16][256] bf16 hi, swizzled
    __shared__ unsigned char xl_lds[2 * 8192];   // dbuf lo
    __shared__ float gates_w[8][16 * 17];        // per-wave [16 batch][16 gcol]

    const int tid = threadIdx.x;
    const int bid = blockIdx.x;
    const int bg = bid & 7;     // XCD-affine
    const int cg = bid >> 3;    // col group 0..15 (32 cols each)
    const int lane = tid & 63;
    const int w = tid >> 6;     // wave 0..7
    const int n15 = lane & 15;
    const int k8 = lane >> 4;
    const int grow = bg * 16;
    // wave owns all 4 gates for 4 h-cols: lane -> (batch myb, col mycol)
    const int gc = n15 & 3;
    const int gsel = n15 >> 2;
    const int myb = k8 * 4 + gsel;
    const int mycol = cg * 32 + w * 4 + gc;

    // ---- one-time: weight fragments. B-frag col n15 -> gate-row R ----
    const int R = (n15 >> 2) * Hdim + mycol;
    short8 whh[16], wihh[8], wihl[8];
    {
        const float* wr = Whh + (size_t)R * Hdim;
#pragma unroll
        for (int kc = 0; kc < 16; kc++) {
            const float* p = wr + kc * 32 + k8 * 8;
            short8 f;
#pragma unroll
            for (int e = 0; e < 8; e++) f[e] = (short)f2bf(p[e]);
            whh[kc] = f;
        }
        const float* wr2 = Wih + (size_t)R * Din;
#pragma unroll
        for (int kc = 0; kc < 8; kc++) {
            const float* p = wr2 + kc * 32 + k8 * 8;
            short8 fh, fl;
#pragma unroll
            for (int e = 0; e < 8; e++) {
                float v = p[e];
                unsigned short hi = f2bf(v);
                fh[e] = (short)hi;
                fl[e] = (short)f2bf(v - bf2f(hi));
            }
            wihh[kc] = fh;
            wihl[kc] = fl;
        }
    }
    float bias4[4];
#pragma unroll
    for (int g = 0; g < 4; g++) bias4[g] = bih[g * Hdim + mycol] + bhh[g * Hdim + mycol];

    // ---- prologue: stage x[0] -> buf0; prefetch x[1] -> regs ----
    float4 xr[2];
    {
        const float* xb = x + (size_t)grow * (Tlen * Din);
#pragma unroll
        for (int i = 0; i < 2; i++) {
            int cidx = tid + i * 512;
            int row = cidx >> 6;
            int c4 = cidx & 63;
            xr[i] = *(const float4*)(xb + (size_t)row * (Tlen * Din) + c4 * 4);
        }
        conv_x_to_lds(xr, tid, xh_lds, xl_lds);
#pragma unroll
        for (int i = 0; i < 2; i++) {
            int cidx = tid + i * 512;
            int row = cidx >> 6;
            int c4 = cidx & 63;
            xr[i] = *(const float4*)(xb + (size_t)row * (Tlen * Din) + Din + c4 * 4);
        }
    }
    __syncthreads();

    float c_reg = 0.f, h_last = 0.f;

    for (int t = 0; t < Tlen; ++t) {
        // (1) convert xr (= x[t+1]) into buf[(t+1)&1]
        if (t + 1 < Tlen)
            conv_x_to_lds(xr, tid, xh_lds + ((t + 1) & 1) * 8192,
                          xl_lds + ((t + 1) & 1) * 8192);

        // (2) issue first tagged sweep: 4 x 16B per thread (32KB/WG)
        const unsigned int* hb = hbt + ((size_t)(t & 1) * NBG + bg) * 8192;
        const unsigned int* p0 = hb + (size_t)tid * 4;
        const unsigned int* p1 = hb + (size_t)(tid + 512) * 4;
        const unsigned int* p2 = hb + (size_t)(tid + 1024) * 4;
        const unsigned int* p3 = hb + (size_t)(tid + 1536) * 4;
        uint4v r0, r1, r2, r3;
        if (t > 0) {
            asm volatile(
                "global_load_dwordx4 %0, %4, off sc0 sc1\n\t"
                "global_load_dwordx4 %1, %5, off sc0 sc1\n\t"
                "global_load_dwordx4 %2, %6, off sc0 sc1\n\t"
                "global_load_dwordx4 %3, %7, off sc0 sc1"
                : "=&v"(r0), "=&v"(r1), "=&v"(r2), "=&v"(r3)
                : "v"(p0), "v"(p1), "v"(p2), "v"(p3)
                : "memory");
        }

        // (3) x-side MFMAs on buf[t&1] (cover the sweep flight)
        unsigned char* xh = xh_lds + (t & 1) * 8192;
        unsigned char* xl = xl_lds + (t & 1) * 8192;
        f32x4 acc0 = {0.f, 0.f, 0.f, 0.f}, acc1 = {0.f, 0.f, 0.f, 0.f};
#pragma unroll
        for (int kc = 0; kc < 8; kc++) {
            int a = ((n15 << 9) + (kc << 6) + (k8 << 4)) ^ ((n15 & 7) << 4);
            short8 xhv = *(const short8*)(xh + a);
            short8 xlv = *(const short8*)(xl + a);
            acc0 = __builtin_amdgcn_mfma_f32_16x16x32_bf16(xhv, wihh[kc], acc0, 0, 0, 0);
            acc1 = __builtin_amdgcn_mfma_f32_16x16x32_bf16(xlv, wihh[kc], acc1, 0, 0, 0);
            if (kc & 1)
                acc1 = __builtin_amdgcn_mfma_f32_16x16x32_bf16(xhv, wihl[kc], acc1, 0, 0, 0);
            else
                acc0 = __builtin_amdgcn_mfma_f32_16x16x32_bf16(xhv, wihl[kc], acc0, 0, 0, 0);
        }

        // (4) validate tags -> h_lds; PARALLEL batch retry of failed chunks
        if (t > 0) {
            const unsigned want = (unsigned)t;
            asm volatile("s_waitcnt vmcnt(0)" ::: "memory");
            __builtin_amdgcn_sched_barrier(0);
            unsigned need = 0;
            if (chunk_ok(r0, want)) chunk_to_lds(r0, tid, h_lds); else need |= 1u;
            if (chunk_ok(r1, want)) chunk_to_lds(r1, tid + 512, h_lds); else need |= 2u;
            if (chunk_ok(r2, want)) chunk_to_lds(r2, tid + 1024, h_lds); else need |= 4u;
            if (chunk_ok(r3, want)) chunk_to_lds(r3, tid + 1536, h_lds); else need |= 8u;
            int rounds = 0;
            while (need && ++rounds < (1 << 14)) {  // per-lane independent
                if (rounds > 6) __builtin_amdgcn_s_sleep(2);
                // re-issue ALL pending loads in parallel, single wait
                if (need & 1u)
                    asm volatile("global_load_dwordx4 %0, %1, off sc0 sc1"
                                 : "=&v"(r0) : "v"(p0) : "memory");
                if (need & 2u)
                    asm volatile("global_load_dwordx4 %0, %1, off sc0 sc1"
                                 : "=&v"(r1) : "v"(p1) : "memory");
                if (need & 4u)
                    asm volatile("global_load_dwordx4 %0, %1, off sc0 sc1"
                                 : "=&v"(r2) : "v"(p2) : "memory");
                if (need & 8u)
                    asm volatile("global_load_dwordx4 %0, %1, off sc0 sc1"
                                 : "=&v"(r3) : "v"(p3) : "memory");
                asm volatile("s_waitcnt vmcnt(0)" ::: "memory");
                __builtin_amdgcn_sched_barrier(0);
                if ((need & 1u) && chunk_ok(r0, want)) {
                    chunk_to_lds(r0, tid, h_lds);
                    need &= ~1u;
                }
                if ((need & 2u) && chunk_ok(r1, want)) {
                    chunk_to_lds(r1, tid + 512, h_lds);
                    need &= ~2u;
                }
                if ((need & 4u) && chunk_ok(r2, want)) {
                    chunk_to_lds(r2, tid + 1024, h_lds);
                    need &= ~4u;
                }
                if ((need & 8u) && chunk_ok(r3, want)) {
                    chunk_to_lds(r3, tid + 1536, h_lds);
                    need &= ~8u;
                }
            }
        } else {
#pragma unroll
            for (int i = 0; i < 4; i++) {
                int c = tid + i * 512;
                int row = c >> 7;
                int a = ((row << 10) + ((c & 127) << 3)) ^ ((row & 7) << 4);
                *(unsigned long long*)(h_lds + a) = 0ULL;
            }
        }
        __syncthreads();  // A: h_lds ready

        // (5) h-side MFMAs
#pragma unroll
        for (int kc = 0; kc < 16; kc++) {
            short8 a = *(const short8*)(h_lds + (((n15 << 10) + (kc << 6) + (k8 << 4)) ^
                                                ((n15 & 7) << 4)));
            if (kc & 1)
                acc1 = __builtin_amdgcn_mfma_f32_16x16x32_bf16(a, whh[kc], acc1, 0, 0, 0);
            else
                acc0 = __builtin_amdgcn_mfma_f32_16x16x32_bf16(a, whh[kc], acc0, 0, 0, 0);
        }

        // (6) prefetch x[t+2] (covered by cell phase; consumed at (1) next step)
        if (t + 2 < Tlen) {
            const float* xb = x + (size_t)grow * (Tlen * Din) + (size_t)(t + 2) * Din;
#pragma unroll
            for (int i = 0; i < 2; i++) {
                int cidx = tid + i * 512;
                int row = cidx >> 6;
                int c4 = cidx & 63;
                xr[i] = *(const float4*)(xb + (size_t)row * (Tlen * Din) + c4 * 4);
            }
        }

        // (7) gates to wave-PRIVATE LDS tile; cell update; fire-and-forget publish
        float* gt = gates_w[w];
#pragma unroll
        for (int j2 = 0; j2 < 4; j2++) gt[(k8 * 4 + j2) * 17 + n15] = acc0[j2] + acc1[j2];
        {
            float pre[4];
#pragma unroll
            for (int g = 0; g < 4; g++) pre[g] = gt[myb * 17 + g * 4 + gc] + bias4[g];
            float ig = sigm_f(pre[0]);
            float fg = sigm_f(pre[1]);
            float gg = tanh_f(pre[2]);
            float og = sigm_f(pre[3]);
            c_reg = fg * c_reg + ig * gg;
            h_last = og * tanh_f(c_reg);
            unsigned int word = ((unsigned int)f2bf(h_last) << 16) | (unsigned)(t + 1);
            unsigned int* dst = hbt + ((size_t)((t + 1) & 1) * NBG + bg) * 8192 +
                                (size_t)myb * Hdim + mycol;
            __hip_atomic_store(dst, word, __ATOMIC_RELAXED, __HIP_MEMORY_SCOPE_AGENT);
        }
        __syncthreads();  // C: clears LDS WAR hazards for next step
    }

    hT[(size_t)(grow + myb) * Hdim + mycol] = h_last;
}

__global__ __launch_bounds__(256) void out_proj(const float* __restrict__ hT,
                                                const float* __restrict__ Wout,
                                                const float* __restrict__ bout,
                                                float* __restrict__ out) {
    __shared__ float h_s[16 * 512];
    __shared__ float w_s[64 * 69];
    const int tid = threadIdx.x;
    const int bt = blockIdx.x >> 2;
    const int ot = blockIdx.x & 3;
#pragma unroll
    for (int i = 0; i < 8; i++) {
        int cidx = tid + i * 256;
        int row = cidx >> 7;
        int c4 = cidx & 127;
        *(float4*)(&h_s[row * 512 + c4 * 4]) =
            *(const float4*)(hT + (size_t)(bt * 16 + row) * 512 + c4 * 4);
    }
    const int o = tid & 63;
    const int bq = tid >> 6;
    float acc[4] = {0.f, 0.f, 0.f, 0.f};
    for (int kc = 0; kc < 8; kc++) {
        __syncthreads();
#pragma unroll
        for (int i = 0; i < 4; i++) {
            int cidx = tid + i * 256;
            int row = cidx >> 4;
            int c4 = cidx & 15;
            float4 v = *(const float4*)(Wout + (size_t)(ot * 64 + row) * 512 + kc * 64 +
                                        c4 * 4);
            float* dst = &w_s[row * 69 + c4 * 4];
            dst[0] = v.x;
            dst[1] = v.y;
            dst[2] = v.z;
            dst[3] = v.w;
        }
        __syncthreads();
#pragma unroll 16
        for (int k = 0; k < 64; k++) {
            float wv = w_s[o * 69 + k];
#pragma unroll
            for (int bi = 0; bi < 4; bi++)
                acc[bi] += h_s[(bq * 4 + bi) * 512 + kc * 64 + k] * wv;
        }
    }
    float bo = bout[ot * 64 + o];
#pragma unroll
    for (int bi = 0; bi < 4; bi++)
        out[(size_t)(bt * 16 + bq * 4 + bi) * 256 + ot * 64 + o] = acc[bi] + bo;
}

extern "C" void kernel_launch(void* const* d_in, const int* in_sizes, int n_in,
                              void* d_out, int out_size, void* d_ws, size_t ws_size,
                              hipStream_t stream) {
    const float* x = (const float*)d_in[0];
    const float* Wih = (const float*)d_in[1];
    const float* Whh = (const float*)d_in[2];
    const float* bih = (const float*)d_in[3];
    const float* bhh = (const float*)d_in[4];
    const float* Wout = (const float*)d_in[5];
    const float* bout = (const float*)d_in[6];
    float* out = (float*)d_out;

    char* ws = (char*)d_ws;
    unsigned int* hbt = (unsigned int*)ws;
    float* hT = (float*)(ws + HT_OFF);

    hipMemsetAsync(hbt, 0, HBT_BYTES, stream);  // clear tags: replay determinism
    lstm_persist<<<dim3(NBG * NCG), dim3(512), 0, stream>>>(x, Wih, Whh, bih, bhh, hbt,
                                                            hT);
    out_proj<<<dim3(32), dim3(256), 0, stream>>>(hT, Wout, bout, out);
}